// Round 5
// baseline (464.012 us; speedup 1.0000x reference)
//
#include <hip/hip_runtime.h>
#include <math.h>

#define BB 16
#define DMODEL 2048
#define NHEAD 32
#define SKV 4096
#define HDIM 64
#define BH (BB*NHEAD)   /* 512 */
#define NSTRIP 16
#define SREC 68         /* floats per (bh,strip) record: M,S,pad,pad,acc[64] */

typedef float f4 __attribute__((ext_vector_type(4)));

// ---------------------------------------------------------------------------
// partial GEMM: part[tile_y][b][o] = sum_{i in tile of 64} src[b][i]*W[i][o]
// grid (2, 32, nmat), block 256, thread owns 4 consecutive o-columns.
// ---------------------------------------------------------------------------
__global__ __launch_bounds__(256) void gemm_part(
    const float* __restrict__ src,
    const float* __restrict__ Wa, const float* __restrict__ Wb,
    const float* __restrict__ Wc,
    float* __restrict__ pa, float* __restrict__ pb, float* __restrict__ pc) {
  const float* W = (blockIdx.z == 0) ? Wa : ((blockIdx.z == 1) ? Wb : Wc);
  float* part    = (blockIdx.z == 0) ? pa : ((blockIdx.z == 1) ? pb : pc);
  __shared__ float xs[16][64];
  int tid = threadIdx.x;
  int i0 = blockIdx.y * 64;
  int o  = blockIdx.x * 1024 + tid * 4;
  {
    int t = tid * 4;
    int b = t >> 6, i = t & 63;
    *(f4*)&xs[b][i] = *(const f4*)&src[b * DMODEL + i0 + i];
  }
  __syncthreads();
  f4 acc[16];
#pragma unroll
  for (int b = 0; b < 16; ++b) acc[b] = (f4)0.f;
#pragma unroll 8
  for (int i = 0; i < 64; ++i) {
    f4 w = *(const f4*)&W[(size_t)(i0 + i) * DMODEL + o];
#pragma unroll
    for (int b = 0; b < 16; ++b) acc[b] += xs[b][i] * w;
  }
  float* p = part + (size_t)blockIdx.y * (16 * DMODEL) + o;
#pragma unroll
  for (int b = 0; b < 16; ++b) *(f4*)&p[b * DMODEL] = acc[b];
}

// ---------------------------------------------------------------------------
// reduce partials over 32 tiles + bias -> dst.  grid (128, nmat)
// ---------------------------------------------------------------------------
__global__ __launch_bounds__(256) void gemm_reduce(
    const float* __restrict__ pa, const float* __restrict__ pb,
    const float* __restrict__ pc,
    const float* __restrict__ ba, const float* __restrict__ bb,
    const float* __restrict__ bc,
    float* __restrict__ da, float* __restrict__ db, float* __restrict__ dc) {
  const float* p    = (blockIdx.y == 0) ? pa : ((blockIdx.y == 1) ? pb : pc);
  const float* bias = (blockIdx.y == 0) ? ba : ((blockIdx.y == 1) ? bb : bc);
  float* dst        = (blockIdx.y == 0) ? da : ((blockIdx.y == 1) ? db : dc);
  int idx = blockIdx.x * 256 + threadIdx.x;
  float s = bias[idx & (DMODEL - 1)];
#pragma unroll 8
  for (int t = 0; t < 32; ++t) s += p[(size_t)t * (16 * DMODEL) + idx];
  dst[idx] = s;
}

// ---------------------------------------------------------------------------
// Fused KV stream: per (bh, strip of 256 rows):
//   phase A: K copy + scores (in regs) + block-local (M, Sexp)
//   phase B: V copy + unnormalized acc = sum exp(s - M_blk) * v
// Emits pstat record [M, S, pad, pad, acc[64]] per strip. Flash-style exact.
// ---------------------------------------------------------------------------
__global__ __launch_bounds__(256) void kv_fused(
    const float* __restrict__ cacheK, const float* __restrict__ cacheV,
    const float* __restrict__ knew, const float* __restrict__ vnew,
    const float* __restrict__ qv, const int* __restrict__ last_pos,
    float* __restrict__ outK, float* __restrict__ outV,
    float* __restrict__ pstat) {
  int bh = blockIdx.x >> 4;
  int j0 = (blockIdx.x & 15) << 8;
  int b = bh >> 5;
  int lp = last_pos[b];
  int tid = threadIdx.x;
  int wave = tid >> 6, lane = tid & 63, q4 = lane >> 4, l16 = lane & 15;
  int rbase = wave * 4 + q4;
  const f4 qf = ((const f4*)(qv + bh * HDIM))[l16];
  const f4 kn = ((const f4*)(knew + bh * HDIM))[l16];
  const f4 vn = ((const f4*)(vnew + bh * HDIM))[l16];
  size_t base = ((size_t)bh * SKV + j0 + rbase) * 16 + l16;
  const f4* K4 = (const f4*)cacheK + base;
  const f4* V4 = (const f4*)cacheV + base;
  f4* OK4 = (f4*)outK + base;
  f4* OV4 = (f4*)outV + base;
  __shared__ float lm[4], ls[4], part[4][64];

  // ---- phase A: K stream + per-row scores (replicated across l16 group)
  float fv[16];
#pragma unroll
  for (int t = 0; t < 16; ++t) {
    int j = j0 + rbase + t * 16;
    f4 kv = __builtin_nontemporal_load(&K4[t * 256]);
    if (j == lp) kv = kn;
    __builtin_nontemporal_store(kv, &OK4[t * 256]);
    float p = qf.x * kv.x + qf.y * kv.y + qf.z * kv.z + qf.w * kv.w;
    p += __shfl_xor(p, 1);
    p += __shfl_xor(p, 2);
    p += __shfl_xor(p, 4);
    p += __shfl_xor(p, 8);
    fv[t] = (j <= lp) ? p * 0.125f : -1e30f;
  }
  float m = fv[0];
#pragma unroll
  for (int t = 1; t < 16; ++t) m = fmaxf(m, fv[t]);
  m = fmaxf(m, __shfl_xor(m, 16));
  m = fmaxf(m, __shfl_xor(m, 32));
  if (lane == 0) lm[wave] = m;
  __syncthreads();
  float M = fmaxf(fmaxf(lm[0], lm[1]), fmaxf(lm[2], lm[3]));
  float se = 0.f;
#pragma unroll
  for (int t = 0; t < 16; ++t) { fv[t] = __expf(fv[t] - M); se += fv[t]; }
  se += __shfl_xor(se, 16);   // sum across q4 row-groups (l16 replicas not summed)
  se += __shfl_xor(se, 32);
  if (lane == 0) ls[wave] = se;

  // ---- phase B: V stream + weighted accumulate
  f4 acc = (f4)0.f;
#pragma unroll
  for (int t = 0; t < 16; ++t) {
    int j = j0 + rbase + t * 16;
    f4 vv = __builtin_nontemporal_load(&V4[t * 256]);
    if (j == lp) vv = vn;
    __builtin_nontemporal_store(vv, &OV4[t * 256]);
    acc += fv[t] * vv;
  }
  acc.x += __shfl_xor(acc.x, 16); acc.x += __shfl_xor(acc.x, 32);
  acc.y += __shfl_xor(acc.y, 16); acc.y += __shfl_xor(acc.y, 32);
  acc.z += __shfl_xor(acc.z, 16); acc.z += __shfl_xor(acc.z, 32);
  acc.w += __shfl_xor(acc.w, 16); acc.w += __shfl_xor(acc.w, 32);
  if (q4 == 0) ((f4*)part[wave])[l16] = acc;
  __syncthreads();
  float* rec = pstat + (size_t)blockIdx.x * SREC;
  if (tid < 64) {
    rec[4 + tid] = part[0][tid] + part[1][tid] + part[2][tid] + part[3][tid];
  } else if (tid == 64) {
    rec[0] = M;
    rec[1] = ls[0] + ls[1] + ls[2] + ls[3];
  }
}

// ---------------------------------------------------------------------------
// Wo GEMM with fused strip-combine: i-tile blockIdx.y == head h; the xs
// staging combines the 16 strip records for bh=(b,h) exactly:
//   attn[b][h*64+d] = sum_s e^{M_s-M} acc_s[d] / sum_s e^{M_s-M} S_s
// grid (2, 32), block 256.
// ---------------------------------------------------------------------------
__global__ __launch_bounds__(256) void attn_gemm_part(
    const float* __restrict__ pstat, const float* __restrict__ Wo,
    float* __restrict__ po) {
  __shared__ float xs[16][64];
  int tid = threadIdx.x;
  int h = blockIdx.y;
  {
    int g = tid >> 4, u = tid & 15;        // g = batch b, u = dim quad
    const float* prec = pstat + (size_t)(g * NHEAD + h) * NSTRIP * SREC;
    float M = -1e30f;
#pragma unroll
    for (int s = 0; s < 16; ++s) M = fmaxf(M, prec[s * SREC]);
    float es[16];
    float D = 0.f;
#pragma unroll
    for (int s = 0; s < 16; ++s) {
      es[s] = __expf(prec[s * SREC] - M);
      D += es[s] * prec[s * SREC + 1];
    }
    float invD = 1.f / D;
    f4 a = (f4)0.f;
#pragma unroll
    for (int s = 0; s < 16; ++s)
      a += es[s] * *(const f4*)&prec[s * SREC + 4 + u * 4];
    *(f4*)&xs[g][u * 4] = a * invD;
  }
  __syncthreads();
  int o = blockIdx.x * 1024 + tid * 4;
  int i0 = h * 64;
  f4 acc[16];
#pragma unroll
  for (int b = 0; b < 16; ++b) acc[b] = (f4)0.f;
#pragma unroll 8
  for (int i = 0; i < 64; ++i) {
    f4 w = *(const f4*)&Wo[(size_t)(i0 + i) * DMODEL + o];
#pragma unroll
    for (int b = 0; b < 16; ++b) acc[b] += xs[b][i] * w;
  }
  float* p = po + (size_t)blockIdx.y * (16 * DMODEL) + o;
#pragma unroll
  for (int b = 0; b < 16; ++b) *(f4*)&p[b * DMODEL] = acc[b];
}

// ---------------------------------------------------------------------------
extern "C" void kernel_launch(void* const* d_in, const int* in_sizes, int n_in,
                              void* d_out, int out_size, void* d_ws, size_t ws_size,
                              hipStream_t stream) {
  const float* x        = (const float*)d_in[0];
  const int*   last_pos = (const int*)d_in[1];
  // d_in[2] = mask (recomputed from last_pos, ignored)
  const float* Wq = (const float*)d_in[3];
  const float* bq = (const float*)d_in[4];
  const float* Wk = (const float*)d_in[5];
  const float* bk = (const float*)d_in[6];
  const float* Wv = (const float*)d_in[7];
  const float* bv = (const float*)d_in[8];
  const float* Wo = (const float*)d_in[9];
  const float* bo = (const float*)d_in[10];
  const float* cacheK = (const float*)d_in[11];
  const float* cacheV = (const float*)d_in[12];

  float* out  = (float*)d_out;                      // 32768
  float* outK = out + (size_t)BB * DMODEL;
  float* outV = outK + (size_t)BH * SKV * HDIM;

  float* ws    = (float*)d_ws;
  float* q     = ws;                                // 32768
  float* k     = ws + 32768;
  float* v     = ws + 65536;
  float* pstat = ws + 98304;                        // 8192*68 = 557056
  float* big   = ws + 98304 + 8192 * SREC;          // 3x1048576 region
  float* pq = big;
  float* pk = big + 1048576;
  float* pv = big + 2097152;
  float* po = big;                                  // reuse after kv_fused

  gemm_part<<<dim3(2, 32, 3), 256, 0, stream>>>(x, Wq, Wk, Wv, pq, pk, pv);
  gemm_reduce<<<dim3(128, 3), 256, 0, stream>>>(pq, pk, pv, bq, bk, bv, q, k, v);
  kv_fused<<<8192, 256, 0, stream>>>(cacheK, cacheV, k, v, q, last_pos,
                                     outK, outV, pstat);
  attn_gemm_part<<<dim3(2, 32), 256, 0, stream>>>(pstat, Wo, po);
  gemm_reduce<<<dim3(128, 1), 256, 0, stream>>>(po, po, po, bo, bo, bo,
                                                out, out, out);
}